// Round 13
// baseline (600.215 us; speedup 1.0000x reference)
//
#include <hip/hip_runtime.h>

typedef unsigned short u16;
typedef __attribute__((ext_vector_type(8))) short s16x8;
typedef __attribute__((ext_vector_type(4))) float f32x4;
typedef __attribute__((ext_vector_type(4))) unsigned u32x4;
typedef __attribute__((ext_vector_type(2))) unsigned u32x2;

#define N_CLLN 120000
#define B_CLLN 200
#define NPG    600
#define E_CLLN 1200000
#define N_MOLN 64
#define E_MOLN 256
#define N_BION 19000
#define E_BION 600000
#define NTOT   (N_CLLN + N_BION)
#define ETOT   (E_CLLN + E_BION)
#define HDIM   200
#define NT     13    // 13*16 = 208 >= 200 output cols
#define FCAP   2048  // bio frontier cap
#define ST1    136   // LDS row stride (u16) for 128-col tile: 272B, 16B-aligned, 2-way banks
#define ST2    216   // LDS row stride (u16) for 200-col tile: 432B, 16B-aligned, 2-way banks

__device__ __forceinline__ float b2f(u16 u){ return __uint_as_float(((unsigned)u)<<16); }
__device__ __forceinline__ float u2f_lo(unsigned u){ return __uint_as_float(u<<16); }
__device__ __forceinline__ float u2f_hi(unsigned u){ return __uint_as_float(u & 0xFFFF0000u); }
__device__ __forceinline__ u16 f2b(float f){
  unsigned x = __float_as_uint(f);
  return (u16)((x + 0x7fffu + ((x>>16)&1u)) >> 16);
}

// ================= combined CSR build (cll nodes 0..N_CLLN-1, bio at +N_CLLN) ==========
// hist captures each edge's within-bucket slot -> scatter needs no atomics.
__global__ void hist_all(const int* __restrict__ eC, const int* __restrict__ eB,
                         int* __restrict__ cnt, int* __restrict__ eidx){
  int i = blockIdx.x*blockDim.x + threadIdx.x;
  if (i < E_CLLN)      eidx[i] = atomicAdd(&cnt[eC[E_CLLN + i]], 1);
  else if (i < ETOT)   eidx[i] = atomicAdd(&cnt[N_CLLN + eB[E_BION + (i - E_CLLN)]], 1);
}
// scan1 also emits dinv = rsqrt(cnt+1)
__global__ void scan1(const int* __restrict__ cnt, float* __restrict__ dinv,
                      int* __restrict__ rows, int* __restrict__ bsum, int N){
  __shared__ int sh[256];
  int b = blockIdx.x, t = threadIdx.x;
  int base = b*1024 + t*4;
  int v[4]; int s = 0;
#pragma unroll
  for (int i=0;i<4;i++){
    int idx = base+i;
    v[i] = (idx<N)?cnt[idx]:0;
    if (idx<N) dinv[idx] = rsqrtf((float)v[i] + 1.0f);
    s += v[i];
  }
  sh[t] = s; __syncthreads();
  for (int off=1; off<256; off<<=1){
    int x = (t>=off)? sh[t-off] : 0; __syncthreads();
    sh[t] += x; __syncthreads();
  }
  int run = (t==0)? 0 : sh[t-1];
#pragma unroll
  for (int i=0;i<4;i++){ int idx = base+i; if (idx<N) rows[idx] = run; run += v[i]; }
  if (t==255) bsum[b] = sh[255];
}
__global__ void scan2(int* __restrict__ bsum, int nb){
  __shared__ int sh[256];
  int t = threadIdx.x;
  sh[t] = (t<nb)? bsum[t] : 0; __syncthreads();
  for (int off=1; off<256; off<<=1){
    int x = (t>=off)? sh[t-off] : 0; __syncthreads();
    sh[t] += x; __syncthreads();
  }
  if (t<nb) bsum[t] = (t==0)? 0 : sh[t-1];
}
__global__ void scan3(int* __restrict__ rows, const int* __restrict__ bsum, int N){
  int i = blockIdx.x*blockDim.x + threadIdx.x;
  if (i<N) rows[i] += bsum[i>>10];
}
__global__ void scatter_all(const int* __restrict__ eC, const int* __restrict__ eB,
                            const int* __restrict__ rows, const int* __restrict__ eidx,
                            int* __restrict__ csr){
  int i = blockIdx.x*blockDim.x + threadIdx.x;
  if (i < E_CLLN){
    int d = eC[E_CLLN + i];
    csr[rows[d] + eidx[i]] = eC[i];
  } else if (i < ETOT){
    int j = i - E_CLLN;
    int d = N_CLLN + eB[E_BION + j];
    csr[rows[d] + eidx[i]] = eB[j];
  }
}

// ===== prescale (cll): X'[r] = dinv[r]*X[r], fp32[N,128] -> bf16[N,128] =====
__global__ void prescale128(const float* __restrict__ x, const float* __restrict__ dinv,
                            u16* __restrict__ out, int N){
  int idx = blockIdx.x*blockDim.x + threadIdx.x;
  if (idx >= N*16) return;
  int r = idx >> 4, c8 = (idx & 15) << 3;
  float dv = dinv[r];
  const float* p = x + (size_t)r*128 + c8;
  f32x4 v0 = *(const f32x4*)p;
  f32x4 v1 = *(const f32x4*)(p+4);
  u32x4 w;
  w[0] = (unsigned)f2b(v0[0]*dv) | ((unsigned)f2b(v0[1]*dv)<<16);
  w[1] = (unsigned)f2b(v0[2]*dv) | ((unsigned)f2b(v0[3]*dv)<<16);
  w[2] = (unsigned)f2b(v1[0]*dv) | ((unsigned)f2b(v1[1]*dv)<<16);
  w[3] = (unsigned)f2b(v1[2]*dv) | ((unsigned)f2b(v1[3]*dv)<<16);
  *(u32x4*)(out + (size_t)r*128 + c8) = w;
}

// ===== single pack kernel: Pc1 (K=128, 4 steps) + Pc2 (K=200, 7 steps) =====
__device__ __forceinline__ void pack_one(const float* W, u16* Bp, int K, int idx){
  int l  = idx & 63;
  int nt = (idx >> 6) % NT;
  int kk = idx / (64*NT);
  int n  = nt*16 + (l & 15);
  int k0 = kk*32 + (l>>4)*8;
  u16 v[8];
#pragma unroll
  for (int e=0;e<8;e++){
    int k = k0 + e;
    v[e] = (k < K && n < HDIM) ? f2b(W[(size_t)k*HDIM + n]) : (u16)0;
  }
#pragma unroll
  for (int e=0;e<8;e++) Bp[(size_t)idx*8 + e] = v[e];
}
__global__ void pack_both(const float* __restrict__ Wc1, u16* __restrict__ Pc1,
                          const float* __restrict__ Wc2, u16* __restrict__ Pc2){
  int idx = blockIdx.x*blockDim.x + threadIdx.x;
  const int t1 = 4*NT*64;
  if (idx < t1) pack_one(Wc1, Pc1, 128, idx);
  else if (idx < t1 + 7*NT*64) pack_one(Wc2, Pc2, 200, idx - t1);
}

// ===== FUSED layer 1: gather(XS,128 cols)->LDS, MFMA, out = dinv*relu(acc+bias) bf16 ====
__global__ __launch_bounds__(256) void fused_h1(
    const u16* __restrict__ XS, const float* __restrict__ dinv,
    const int* __restrict__ rows, const int* __restrict__ csr,
    const u16* __restrict__ Bp, const float* __restrict__ bias,
    u16* __restrict__ Out, int M, int E)
{
  __shared__ u16 tile[64*ST1];
  const int w = threadIdx.x >> 6;
  const int l = threadIdx.x & 63;
  const int half = l >> 5, lh = l & 31;
  const int lm = l & 15, kg = l >> 4;
  const int base = blockIdx.x*64;
  const unsigned* srcb = (const unsigned*)XS;
  // ---- gather phase: wave w fills local rows w*16 .. w*16+15 ----
  for (int r = 0; r < 16; ++r){
    int node = base + w*16 + r;
    int nc = node < M ? node : M-1;
    float dv = dinv[nc];
    int e0 = rows[nc];
    int e1 = (nc+1 < M) ? rows[nc+1] : E;
    float a0=0.f, a1=0.f, a2=0.f, a3=0.f;
    if (half == 0){
      u32x2 sv = *((const u32x2*)(srcb + (size_t)nc*64) + lh);
      a0 = u2f_lo(sv[0]); a1 = u2f_hi(sv[0]);
      a2 = u2f_lo(sv[1]); a3 = u2f_hi(sv[1]);
    }
    for (int b0 = e0; b0 < e1; b0 += 64){
      int n = e1 - b0;
      int cnt = n < 64 ? n : 64;
      int myv = (l < cnt) ? csr[b0 + l] : 0;
      int i = 0;
      for (; i + 15 < cnt; i += 16){
        u32x2 P[8];
#pragma unroll
        for (int u=0;u<8;u++){
          int s = __shfl(myv, i + 2*u + half);
          P[u] = *((const u32x2*)(srcb + (size_t)s*64) + lh);
        }
#pragma unroll
        for (int u=0;u<8;u++){
          a0 += u2f_lo(P[u][0]); a1 += u2f_hi(P[u][0]);
          a2 += u2f_lo(P[u][1]); a3 += u2f_hi(P[u][1]);
        }
      }
      for (; i < cnt; i += 2){
        int idx = i + half;
        int ci = idx < cnt ? idx : cnt-1;
        int s = __shfl(myv, ci);
        u32x2 P = *((const u32x2*)(srcb + (size_t)s*64) + lh);
        if (idx < cnt){
          a0 += u2f_lo(P[0]); a1 += u2f_hi(P[0]);
          a2 += u2f_lo(P[1]); a3 += u2f_hi(P[1]);
        }
      }
    }
    a0 += __shfl_xor(a0, 32); a1 += __shfl_xor(a1, 32);
    a2 += __shfl_xor(a2, 32); a3 += __shfl_xor(a3, 32);
    if (half == 0){
      u32x2 wv;
      wv[0] = (unsigned)f2b(a0*dv) | ((unsigned)f2b(a1*dv) << 16);
      wv[1] = (unsigned)f2b(a2*dv) | ((unsigned)f2b(a3*dv) << 16);
      *((u32x2*)((unsigned*)(tile + (size_t)(w*16+r)*ST1)) + lh) = wv;
    }
  }
  __syncthreads();
  // ---- GEMM phase: one A-frag per wave, K=128 ----
  f32x4 acc[NT] = {};
  const u16* Arow = tile + (size_t)(w*16 + lm)*ST1;
#pragma unroll
  for (int kk=0; kk<4; ++kk){
    s16x8 a = *(const s16x8*)(Arow + kk*32 + kg*8);
    const u16* bp = Bp + ((size_t)kk*NT*64 + l)*8;
#pragma unroll
    for (int t=0;t<NT;t++){
      s16x8 b = *(const s16x8*)(bp + t*512);
      acc[t] = __builtin_amdgcn_mfma_f32_16x16x32_bf16(a, b, acc[t], 0, 0, 0);
    }
  }
  int orow = base + w*16 + kg*4;   // C/D: col=lane&15, row=(lane>>4)*4+j
  float scj[4];
#pragma unroll
  for (int j=0;j<4;j++){ int r = orow + j; scj[j] = (r < M) ? dinv[r] : 0.f; }
#pragma unroll
  for (int t=0;t<NT;t++){
    int c = t*16 + lm;
    if (c < HDIM){
#pragma unroll
      for (int j=0;j<4;j++){
        int r = orow + j;
        if (r < M){
          float v = fmaxf(acc[t][j] + bias[c], 0.f) * scj[j];
          Out[(size_t)r*HDIM + c] = f2b(v);
        }
      }
    }
  }
}

// ===== FUSED layer 2: gather(BUF1,200 cols)->LDS, MFMA, fused mean-pool epilogue ====
__global__ __launch_bounds__(256) void fused_pool(
    const u16* __restrict__ H1, const float* __restrict__ dinv,
    const int* __restrict__ rows, const int* __restrict__ csr,
    const u16* __restrict__ Bp, const float* __restrict__ bias,
    float* __restrict__ pooled, int M, int E)
{
  __shared__ u16 tile[64*ST2];
  __shared__ float ps[4][2][HDIM+8];
  for (int i = threadIdx.x; i < 4*2*(HDIM+8); i += 256) ((float*)ps)[i] = 0.f;
  const int w = threadIdx.x >> 6;
  const int l = threadIdx.x & 63;
  const int half = l >> 5, lh = l & 31;
  const int lm = l & 15, kg = l >> 4;
  const bool act = lh < 25;
  const int base = blockIdx.x*64;
  const unsigned* srcb = (const unsigned*)H1;
  // ---- gather phase ----
  for (int r = 0; r < 16; ++r){
    int node = base + w*16 + r;
    int nc = node < M ? node : M-1;
    float dv = dinv[nc];
    int e0 = rows[nc];
    int e1 = (nc+1 < M) ? rows[nc+1] : E;
    float a0=0.f,a1=0.f,a2=0.f,a3=0.f,a4=0.f,a5=0.f,a6=0.f,a7=0.f;
    if (half == 0 && act){
      u32x4 sv = *((const u32x4*)(srcb + (size_t)nc*100) + lh);
      a0 = u2f_lo(sv[0]); a1 = u2f_hi(sv[0]);
      a2 = u2f_lo(sv[1]); a3 = u2f_hi(sv[1]);
      a4 = u2f_lo(sv[2]); a5 = u2f_hi(sv[2]);
      a6 = u2f_lo(sv[3]); a7 = u2f_hi(sv[3]);
    }
    for (int b0 = e0; b0 < e1; b0 += 64){
      int n = e1 - b0;
      int cnt = n < 64 ? n : 64;
      int myv = (l < cnt) ? csr[b0 + l] : 0;
      int i = 0;
      for (; i + 15 < cnt; i += 16){
        int ss[8];
#pragma unroll
        for (int u=0;u<8;u++) ss[u] = __shfl(myv, i + 2*u + half);
        u32x4 P[8];
#pragma unroll
        for (int u=0;u<8;u++){
          u32x4 z = {0,0,0,0};
          P[u] = act ? *((const u32x4*)(srcb + (size_t)ss[u]*100) + lh) : z;
        }
#pragma unroll
        for (int u=0;u<8;u++){
          a0 += u2f_lo(P[u][0]); a1 += u2f_hi(P[u][0]);
          a2 += u2f_lo(P[u][1]); a3 += u2f_hi(P[u][1]);
          a4 += u2f_lo(P[u][2]); a5 += u2f_hi(P[u][2]);
          a6 += u2f_lo(P[u][3]); a7 += u2f_hi(P[u][3]);
        }
      }
      for (; i < cnt; i += 2){
        int idx = i + half;
        int ci = idx < cnt ? idx : cnt-1;
        int s = __shfl(myv, ci);
        u32x4 P = {0,0,0,0};
        if (act) P = *((const u32x4*)(srcb + (size_t)s*100) + lh);
        if (idx < cnt){
          a0 += u2f_lo(P[0]); a1 += u2f_hi(P[0]);
          a2 += u2f_lo(P[1]); a3 += u2f_hi(P[1]);
          a4 += u2f_lo(P[2]); a5 += u2f_hi(P[2]);
          a6 += u2f_lo(P[3]); a7 += u2f_hi(P[3]);
        }
      }
    }
    a0 += __shfl_xor(a0, 32); a1 += __shfl_xor(a1, 32);
    a2 += __shfl_xor(a2, 32); a3 += __shfl_xor(a3, 32);
    a4 += __shfl_xor(a4, 32); a5 += __shfl_xor(a5, 32);
    a6 += __shfl_xor(a6, 32); a7 += __shfl_xor(a7, 32);
    if (half == 0 && act){
      u32x4 wv;
      wv[0] = (unsigned)f2b(a0*dv) | ((unsigned)f2b(a1*dv) << 16);
      wv[1] = (unsigned)f2b(a2*dv) | ((unsigned)f2b(a3*dv) << 16);
      wv[2] = (unsigned)f2b(a4*dv) | ((unsigned)f2b(a5*dv) << 16);
      wv[3] = (unsigned)f2b(a6*dv) | ((unsigned)f2b(a7*dv) << 16);
      *((u32x4*)((unsigned*)(tile + (size_t)(w*16+r)*ST2)) + lh) = wv;
    }
  }
  __syncthreads();
  // ---- GEMM phase: one A-frag per wave, K=200 (7 steps, guarded) ----
  f32x4 acc[NT] = {};
  const s16x8 az = {0,0,0,0,0,0,0,0};
  const u16* Arow = tile + (size_t)(w*16 + lm)*ST2;
#pragma unroll
  for (int kk=0; kk<7; ++kk){
    int k0 = kk*32 + kg*8;
    s16x8 a = (k0 < HDIM) ? *(const s16x8*)(Arow + k0) : az;
    const u16* bp = Bp + ((size_t)kk*NT*64 + l)*8;
#pragma unroll
    for (int t=0;t<NT;t++){
      s16x8 b = *(const s16x8*)(bp + t*512);
      acc[t] = __builtin_amdgcn_mfma_f32_16x16x32_bf16(a, b, acc[t], 0, 0, 0);
    }
  }
  // ---- pooling epilogue ----
  const int g0 = base / NPG;
  int R0 = base + w*16;
  bool uni = (R0 + 15 < M) && ((R0/NPG) == ((R0+15)/NPG));
  int slotU = (R0/NPG) - g0;
#pragma unroll
  for (int t=0;t<NT;t++){
    int c = t*16 + lm;
    if (c < HDIM){
      float v0 = fmaxf(acc[t][0] + bias[c], 0.f);
      float v1 = fmaxf(acc[t][1] + bias[c], 0.f);
      float v2 = fmaxf(acc[t][2] + bias[c], 0.f);
      float v3 = fmaxf(acc[t][3] + bias[c], 0.f);
      if (uni){
        float s = v0+v1+v2+v3;
        s += __shfl_xor(s, 16);
        s += __shfl_xor(s, 32);
        if (kg == 0) ps[w][slotU][c] += s;
      } else {
        float s0 = 0.f, s1 = 0.f;
        float vv[4] = {v0,v1,v2,v3};
#pragma unroll
        for (int j=0;j<4;j++){
          int r = R0 + kg*4 + j;
          if (r < M){
            if ((r/NPG) - g0 == 0) s0 += vv[j]; else s1 += vv[j];
          }
        }
        s0 += __shfl_xor(s0, 16); s0 += __shfl_xor(s0, 32);
        s1 += __shfl_xor(s1, 16); s1 += __shfl_xor(s1, 32);
        if (kg == 0){ ps[w][0][c] += s0; ps[w][1][c] += s1; }
      }
    }
  }
  __syncthreads();
  for (int i = threadIdx.x; i < 2*HDIM; i += 256){
    int slot = i / HDIM, c = i % HDIM;
    float s = ps[0][slot][c] + ps[1][slot][c] + ps[2][slot][c] + ps[3][slot][c];
    int g = g0 + slot;
    if (g < B_CLLN && s != 0.f) unsafeAtomicAdd(&pooled[g*HDIM + c], s);
  }
}

// ================= xc = pooled/NPG @ Wlc + blc =================
__global__ void xc_kernel(const float* __restrict__ pooled, const float* __restrict__ Wlc,
                          const float* __restrict__ blc, float* __restrict__ xc){
  __shared__ float p[HDIM];
  int b = blockIdx.x, j = threadIdx.x;
  if (j < HDIM) p[j] = pooled[b*HDIM + j] * (1.0f/NPG);
  __syncthreads();
  float s = blc[j];
  for (int k=0;k<HDIM;k++) s += p[k]*Wlc[(size_t)k*256 + j];
  xc[(size_t)b*256 + j] = s;
}

// ===== bio frontier: Y1 rows (f32) for {last} ∪ nbrs(last) only =====
__global__ void bio_front(const float* __restrict__ x_bio, const float* __restrict__ dinvAll,
                          const int* __restrict__ rowAll, const int* __restrict__ csr,
                          float* __restrict__ Y1f, float* __restrict__ dvF){
  const float* dinvB = dinvAll + N_CLLN;
  int g0l = rowAll[NTOT - 1];
  int fcnt = (ETOT - g0l) + 1; if (fcnt > FCAP) fcnt = FCAP;
  int wid = (blockIdx.x*blockDim.x + threadIdx.x) >> 6;
  int nw  = (gridDim.x*blockDim.x) >> 6;
  int l = threadIdx.x & 63;
  for (int k = wid; k < fcnt; k += nw){
    int v = (k == 0) ? (N_BION - 1) : csr[g0l + k - 1];
    float dv = dinvB[v];
    int e0 = rowAll[N_CLLN + v];
    int e1 = (v + 1 < N_BION) ? rowAll[N_CLLN + v + 1] : ETOT;
    float c0 = x_bio[(size_t)v*128 + l]      * dv;
    float c1 = x_bio[(size_t)v*128 + l + 64] * dv;
    for (int e = e0; e < e1; ++e){
      int s = csr[e];
      float ds = dinvB[s];
      c0 += x_bio[(size_t)s*128 + l]      * ds;
      c1 += x_bio[(size_t)s*128 + l + 64] * ds;
    }
    Y1f[(size_t)k*128 + l]      = c0 * dv;
    Y1f[(size_t)k*128 + l + 64] = c1 * dv;
    if (l == 0) dvF[k] = dv;
  }
}

// ===== bio h1-accumulate: parallel over frontier rows =====
__global__ __launch_bounds__(256) void bio_h1acc(
    const float* __restrict__ Y1f, const float* __restrict__ dvF,
    const int* __restrict__ rowAll,
    const float* __restrict__ Wb1, const float* __restrict__ bb1,
    float* __restrict__ Y2acc){
  __shared__ float y1[128];
  int tid = threadIdx.x;
  int g0l = rowAll[NTOT - 1];
  int fcnt = (ETOT - g0l) + 1; if (fcnt > FCAP) fcnt = FCAP;
  for (int k = blockIdx.x; k < fcnt; k += gridDim.x){
    if (tid < 128) y1[tid] = Y1f[(size_t)k*128 + tid];
    __syncthreads();
    if (tid < HDIM){
      float s = bb1[tid];
#pragma unroll 8
      for (int q=0;q<128;q++) s += y1[q]*Wb1[q*HDIM + tid];
      unsafeAtomicAdd(&Y2acc[tid], fmaxf(s, 0.f)*dvF[k]);
    }
    __syncthreads();
  }
}

// ===== bio finish =====
__global__ void bio_fin(const float* __restrict__ Y2acc, const float* __restrict__ dinvAll,
                        const float* __restrict__ Wb2, const float* __restrict__ bb2,
                        const float* __restrict__ Wlb, const float* __restrict__ blb,
                        float* __restrict__ xb){
  __shared__ float Y2[HDIM];
  __shared__ float wv[HDIM];
  int tid = threadIdx.x;
  float dl = dinvAll[NTOT - 1];
  if (tid < HDIM) Y2[tid] = Y2acc[tid] * dl;
  __syncthreads();
  if (tid < HDIM){
    float s = bb2[tid];
#pragma unroll 8
    for (int q=0;q<HDIM;q++) s += Y2[q]*Wb2[q*HDIM + tid];
    wv[tid] = fmaxf(s, 0.f);
  }
  __syncthreads();
  if (tid < 128){
    float s = blb[tid];
#pragma unroll 8
    for (int c=0;c<HDIM;c++) s += wv[c]*Wlb[c*128 + tid];
    xb[tid] = s;
  }
}

// ================= mol branch (multi-block, all fp32) =================
__global__ void mol_agg(const float* __restrict__ x, const int* __restrict__ src,
                        const int* __restrict__ dst, float* __restrict__ a, int E, int F){
  int idx = blockIdx.x*blockDim.x + threadIdx.x;
  if (idx >= E*F) return;
  int e = idx / F, f = idx % F;
  unsafeAtomicAdd(&a[dst[e]*F + f], x[(size_t)src[e]*F + f]);
}
__global__ void mol_l1(const float* __restrict__ x, const float* __restrict__ a1,
                       const float* __restrict__ Wrel, const float* __restrict__ brel,
                       const float* __restrict__ Wroot, float* __restrict__ m1){
  int idx = blockIdx.x*blockDim.x + threadIdx.x;
  if (idx >= N_MOLN*HDIM) return;
  int i = idx / HDIM, c = idx % HDIM;
  float s = brel[c];
  for (int k=0;k<64;k++){
    s += a1[i*64+k]*Wrel[k*HDIM+c];
    s += x[i*64+k]*Wroot[k*HDIM+c];
  }
  m1[idx] = fmaxf(s, 0.f);
}
__global__ void mol_l2(const float* __restrict__ m1, const float* __restrict__ a2,
                       const float* __restrict__ Wrel2, const float* __restrict__ brel2,
                       const float* __restrict__ Wroot2, float* __restrict__ colsum){
  int idx = blockIdx.x*blockDim.x + threadIdx.x;
  if (idx >= N_MOLN*HDIM) return;
  int i = idx / HDIM, c = idx % HDIM;
  float s = brel2[c];
  for (int k=0;k<HDIM;k++){
    s += a2[i*HDIM+k]*Wrel2[k*HDIM+c] + m1[i*HDIM+k]*Wroot2[k*HDIM+c];
  }
  s = fmaxf(s, 0.f);
  unsafeAtomicAdd(&colsum[c], s*(1.0f/N_MOLN));
}
__global__ void mol_head(const float* __restrict__ colsum, const float* __restrict__ Wlm,
                         const float* __restrict__ blm, float* __restrict__ xm){
  int j = threadIdx.x;
  if (j >= 128) return;
  float s = blm[j];
  for (int c=0;c<HDIM;c++) s += colsum[c]*Wlm[c*128+j];
  xm[j] = s;
}

// ================= bilinear score =================
__global__ void score_kernel(const float* __restrict__ xc, const float* __restrict__ W,
                             const float* __restrict__ bias, const float* __restrict__ xm,
                             const float* __restrict__ xb, float* __restrict__ out){
  __shared__ float xd[256];
  __shared__ float u[256];
  int tid = threadIdx.x;
  xd[tid] = (tid < 128) ? xm[tid] : xb[tid-128];
  __syncthreads();
  float s = 0.f;
  for (int j=0;j<256;j++) s += W[(size_t)tid*256 + j]*xd[j];
  u[tid] = s;
  __syncthreads();
  if (tid < B_CLLN){
    float sc = bias[0];
    const float* xr = xc + (size_t)tid*256;
    for (int i=0;i<256;i++) sc += xr[i]*u[i];
    out[tid] = sc;
  }
}

extern "C" void kernel_launch(void* const* d_in, const int* in_sizes, int n_in,
                              void* d_out, int out_size, void* d_ws, size_t ws_size,
                              hipStream_t stream) {
  const float* x_cll = (const float*)d_in[0];
  const float* x_mol = (const float*)d_in[1];
  const float* x_bio = (const float*)d_in[2];
  const int* e_cll = (const int*)d_in[3];
  const int* e_mol = (const int*)d_in[5];
  const int* e_bio = (const int*)d_in[6];
  const float *Wc1=(const float*)d_in[7],  *bc1=(const float*)d_in[8];
  const float *Wc2=(const float*)d_in[9],  *bc2=(const float*)d_in[10];
  const float *Wlc=(const float*)d_in[11], *blc=(const float*)d_in[12];
  const float *Wrel1=(const float*)d_in[13],*brel1=(const float*)d_in[14],*Wroot1=(const float*)d_in[15];
  const float *Wrel2=(const float*)d_in[16],*brel2=(const float*)d_in[17],*Wroot2=(const float*)d_in[18];
  const float *Wlm=(const float*)d_in[19], *blm=(const float*)d_in[20];
  const float *Wb1=(const float*)d_in[21], *bb1=(const float*)d_in[22];
  const float *Wb2=(const float*)d_in[23], *bb2=(const float*)d_in[24];
  const float *Wlb=(const float*)d_in[25], *blb=(const float*)d_in[26];
  const float *Wbl=(const float*)d_in[27], *bias=(const float*)d_in[28];
  float* out = (float*)d_out;

  char* ws = (char*)d_ws;
  size_t o = 0;
  auto alloc = [&](size_t bytes)->char*{
    char* p = ws + o;
    o = (o + bytes + 255) & ~(size_t)255;
    return p;
  };
  u16*   XS    = (u16*)  alloc((size_t)N_CLLN*128*2);
  u16*   BUF1  = (u16*)  alloc((size_t)N_CLLN*HDIM*2 + 512);
  float* dinvA = (float*)alloc((size_t)NTOT*4);
  int*   cntA  = (int*)  alloc((size_t)NTOT*4);     // zeroed
  int*   rowA  = (int*)  alloc((size_t)NTOT*4);
  int*   csrA  = (int*)  alloc((size_t)ETOT*4);
  int*   eidx  = (int*)  alloc((size_t)ETOT*4);
  int*   bsum  = (int*)  alloc(256*4);
  float* pooled= (float*)alloc((size_t)B_CLLN*HDIM*4);   // zeroed
  float* xc    = (float*)alloc((size_t)B_CLLN*256*4);
  float* a1    = (float*)alloc((size_t)(N_MOLN*64 + N_MOLN*HDIM + 2*HDIM)*4);  // zero region
  float* a2    = a1 + N_MOLN*64;
  float* colsum= a2 + N_MOLN*HDIM;
  float* Y2acc = colsum + HDIM;
  float* m1    = (float*)alloc((size_t)N_MOLN*HDIM*4);
  float* xm    = (float*)alloc(128*4);
  float* xb    = (float*)alloc(128*4);
  float* Y1f   = (float*)alloc((size_t)FCAP*128*4);
  float* dvF   = (float*)alloc((size_t)FCAP*4);
  u16* Pc1 = (u16*)alloc((size_t)4*NT*64*8*2);
  u16* Pc2 = (u16*)alloc((size_t)7*NT*64*8*2);
  if (o > ws_size) return;
  (void)in_sizes; (void)n_in; (void)out_size;

  hipMemsetAsync(cntA, 0, (size_t)NTOT*4, stream);
  hipMemsetAsync(pooled, 0, (size_t)B_CLLN*HDIM*4, stream);
  hipMemsetAsync(a1, 0, (size_t)(N_MOLN*64 + N_MOLN*HDIM + 2*HDIM)*4, stream);

  pack_both<<<(11*NT*64+255)/256, 256, 0, stream>>>(Wc1, Pc1, Wc2, Pc2);

  // ---- combined CSR build (atomic-free scatter via eidx; dinv fused into scan1) ----
  hist_all<<<(ETOT+255)/256, 256, 0, stream>>>(e_cll, e_bio, cntA, eidx);
  scan1<<<(NTOT+1023)/1024, 256, 0, stream>>>(cntA, dinvA, rowA, bsum, NTOT);
  scan2<<<1, 256, 0, stream>>>(bsum, (NTOT+1023)/1024);
  scan3<<<(NTOT+255)/256, 256, 0, stream>>>(rowA, bsum, NTOT);
  scatter_all<<<(ETOT+255)/256, 256, 0, stream>>>(e_cll, e_bio, rowA, eidx, csrA);

  const int fcll = (N_CLLN+63)/64;   // 1875

  // ---- cll branch: fully fused pipeline ----
  prescale128<<<(N_CLLN*16+255)/256, 256, 0, stream>>>(x_cll, dinvA, XS, N_CLLN);
  fused_h1<<<fcll, 256, 0, stream>>>(XS, dinvA, rowA, csrA, Pc1, bc1, BUF1, N_CLLN, E_CLLN);
  fused_pool<<<fcll, 256, 0, stream>>>(BUF1, dinvA, rowA, csrA, Pc2, bc2, pooled, N_CLLN, E_CLLN);
  xc_kernel<<<B_CLLN, 256, 0, stream>>>(pooled, Wlc, blc, xc);

  // ---- bio branch: frontier only, parallel tail ----
  bio_front<<<16, 256, 0, stream>>>(x_bio, dinvA, rowA, csrA, Y1f, dvF);
  bio_h1acc<<<64, 256, 0, stream>>>(Y1f, dvF, rowA, Wb1, bb1, Y2acc);
  bio_fin<<<1, 256, 0, stream>>>(Y2acc, dinvA, Wb2, bb2, Wlb, blb, xb);

  // ---- mol branch (multi-block) ----
  mol_agg<<<(E_MOLN*64+255)/256, 256, 0, stream>>>(x_mol, e_mol, e_mol + E_MOLN, a1, E_MOLN, 64);
  mol_l1<<<(N_MOLN*HDIM+255)/256, 256, 0, stream>>>(x_mol, a1, Wrel1, brel1, Wroot1, m1);
  mol_agg<<<(E_MOLN*HDIM+255)/256, 256, 0, stream>>>(m1, e_mol, e_mol + E_MOLN, a2, E_MOLN, HDIM);
  mol_l2<<<(N_MOLN*HDIM+255)/256, 256, 0, stream>>>(m1, a2, Wrel2, brel2, Wroot2, colsum);
  mol_head<<<1, 128, 0, stream>>>(colsum, Wlm, blm, xm);

  // ---- score ----
  score_kernel<<<1, 256, 0, stream>>>(xc, Wbl, bias, xm, xb, out);
}

// Round 14
// 486.833 us; speedup vs baseline: 1.2329x; 1.2329x over previous
//
#include <hip/hip_runtime.h>

typedef unsigned short u16;
typedef __attribute__((ext_vector_type(8))) short s16x8;
typedef __attribute__((ext_vector_type(4))) float f32x4;
typedef __attribute__((ext_vector_type(4))) unsigned u32x4;
typedef __attribute__((ext_vector_type(2))) unsigned u32x2;

#define N_CLLN 120000
#define B_CLLN 200
#define NPG    600
#define E_CLLN 1200000
#define N_MOLN 64
#define E_MOLN 256
#define N_BION 19000
#define E_BION 600000
#define NTOT   (N_CLLN + N_BION)
#define ETOT   (E_CLLN + E_BION)
#define HDIM   200
#define NT     13    // 13*16 = 208 >= 200 output cols
#define FCAP   2048  // bio frontier cap

__device__ __forceinline__ float b2f(u16 u){ return __uint_as_float(((unsigned)u)<<16); }
__device__ __forceinline__ float u2f_lo(unsigned u){ return __uint_as_float(u<<16); }
__device__ __forceinline__ float u2f_hi(unsigned u){ return __uint_as_float(u & 0xFFFF0000u); }
__device__ __forceinline__ u16 f2b(float f){
  unsigned x = __float_as_uint(f);
  return (u16)((x + 0x7fffu + ((x>>16)&1u)) >> 16);
}

// ================= combined CSR build (cll nodes 0..N_CLLN-1, bio at +N_CLLN) ==========
__global__ void hist_all(const int* __restrict__ eC, const int* __restrict__ eB,
                         int* __restrict__ cnt, int* __restrict__ eidx){
  int i = blockIdx.x*blockDim.x + threadIdx.x;
  if (i < E_CLLN)      eidx[i] = atomicAdd(&cnt[eC[E_CLLN + i]], 1);
  else if (i < ETOT)   eidx[i] = atomicAdd(&cnt[N_CLLN + eB[E_BION + (i - E_CLLN)]], 1);
}
// scan1 also emits dinv = rsqrt(cnt+1)
__global__ void scan1(const int* __restrict__ cnt, float* __restrict__ dinv,
                      int* __restrict__ rows, int* __restrict__ bsum, int N){
  __shared__ int sh[256];
  int b = blockIdx.x, t = threadIdx.x;
  int base = b*1024 + t*4;
  int v[4]; int s = 0;
#pragma unroll
  for (int i=0;i<4;i++){
    int idx = base+i;
    v[i] = (idx<N)?cnt[idx]:0;
    if (idx<N) dinv[idx] = rsqrtf((float)v[i] + 1.0f);
    s += v[i];
  }
  sh[t] = s; __syncthreads();
  for (int off=1; off<256; off<<=1){
    int x = (t>=off)? sh[t-off] : 0; __syncthreads();
    sh[t] += x; __syncthreads();
  }
  int run = (t==0)? 0 : sh[t-1];
#pragma unroll
  for (int i=0;i<4;i++){ int idx = base+i; if (idx<N) rows[idx] = run; run += v[i]; }
  if (t==255) bsum[b] = sh[255];
}
__global__ void scan2(int* __restrict__ bsum, int nb){
  __shared__ int sh[256];
  int t = threadIdx.x;
  sh[t] = (t<nb)? bsum[t] : 0; __syncthreads();
  for (int off=1; off<256; off<<=1){
    int x = (t>=off)? sh[t-off] : 0; __syncthreads();
    sh[t] += x; __syncthreads();
  }
  if (t<nb) bsum[t] = (t==0)? 0 : sh[t-1];
}
__global__ void scan3(int* __restrict__ rows, const int* __restrict__ bsum, int N){
  int i = blockIdx.x*blockDim.x + threadIdx.x;
  if (i<N) rows[i] += bsum[i>>10];
}
__global__ void scatter_all(const int* __restrict__ eC, const int* __restrict__ eB,
                            const int* __restrict__ rows, const int* __restrict__ eidx,
                            int* __restrict__ csr){
  int i = blockIdx.x*blockDim.x + threadIdx.x;
  if (i < E_CLLN){
    int d = eC[E_CLLN + i];
    csr[rows[d] + eidx[i]] = eC[i];
  } else if (i < ETOT){
    int j = i - E_CLLN;
    int d = N_CLLN + eB[E_BION + j];
    csr[rows[d] + eidx[i]] = eB[j];
  }
}

// ===== prescale (cll): X'[r] = dinv[r]*X[r], fp32[N,128] -> bf16[N,128] =====
__global__ void prescale128(const float* __restrict__ x, const float* __restrict__ dinv,
                            u16* __restrict__ out, int N){
  int idx = blockIdx.x*blockDim.x + threadIdx.x;
  if (idx >= N*16) return;
  int r = idx >> 4, c8 = (idx & 15) << 3;
  float dv = dinv[r];
  const float* p = x + (size_t)r*128 + c8;
  f32x4 v0 = *(const f32x4*)p;
  f32x4 v1 = *(const f32x4*)(p+4);
  u32x4 w;
  w[0] = (unsigned)f2b(v0[0]*dv) | ((unsigned)f2b(v0[1]*dv)<<16);
  w[1] = (unsigned)f2b(v0[2]*dv) | ((unsigned)f2b(v0[3]*dv)<<16);
  w[2] = (unsigned)f2b(v1[0]*dv) | ((unsigned)f2b(v1[1]*dv)<<16);
  w[3] = (unsigned)f2b(v1[2]*dv) | ((unsigned)f2b(v1[3]*dv)<<16);
  *(u32x4*)(out + (size_t)r*128 + c8) = w;
}

// ===== paired gather over 128-col bf16 rows (256B); clamped 8-pair loads (MLP=16) =====
__global__ __launch_bounds__(256) void gather128(
    const u16* __restrict__ X, const float* __restrict__ dinv,
    const int* __restrict__ rows, const int* __restrict__ csr,
    u16* __restrict__ Y, int N, int E)
{
  int wid = (blockIdx.x*blockDim.x + threadIdx.x) >> 6;
  int l = threadIdx.x & 63;
  if (wid >= N) return;
  int half = l >> 5, lh = l & 31;
  float dv = dinv[wid];
  int e0 = rows[wid];
  int e1 = (wid+1 < N) ? rows[wid+1] : E;
  const unsigned* base = (const unsigned*)X;
  float a0=0.f, a1=0.f, a2=0.f, a3=0.f;
  if (half == 0){
    u32x2 sv = *((const u32x2*)(base + (size_t)wid*64) + lh);
    a0 = u2f_lo(sv[0]); a1 = u2f_hi(sv[0]);
    a2 = u2f_lo(sv[1]); a3 = u2f_hi(sv[1]);
  }
  for (int b0 = e0; b0 < e1; b0 += 64){
    int n = e1 - b0;
    int cnt = n < 64 ? n : 64;
    int myv = (l < cnt) ? csr[b0 + l] : 0;
    for (int i = 0; i < cnt; i += 16){
      u32x2 P[8]; bool vld[8];
#pragma unroll
      for (int u=0;u<8;u++){
        int idx = i + 2*u + half;
        int ci = idx < cnt ? idx : cnt-1;     // clamp: dup loads hit L1
        int s = __shfl(myv, ci);
        P[u] = *((const u32x2*)(base + (size_t)s*64) + lh);
        vld[u] = idx < cnt;
      }
#pragma unroll
      for (int u=0;u<8;u++){
        if (vld[u]){
          a0 += u2f_lo(P[u][0]); a1 += u2f_hi(P[u][0]);
          a2 += u2f_lo(P[u][1]); a3 += u2f_hi(P[u][1]);
        }
      }
    }
  }
  a0 += __shfl_xor(a0, 32); a1 += __shfl_xor(a1, 32);
  a2 += __shfl_xor(a2, 32); a3 += __shfl_xor(a3, 32);
  if (half == 0){
    u32x2 wv;
    wv[0] = (unsigned)f2b(a0*dv) | ((unsigned)f2b(a1*dv) << 16);
    wv[1] = (unsigned)f2b(a2*dv) | ((unsigned)f2b(a3*dv) << 16);
    *((u32x2*)((unsigned*)Y + (size_t)wid*64) + lh) = wv;
  }
}

// ===== paired gather over UNPADDED 200-col rows (400B); clamped 8-pair loads =====
__global__ __launch_bounds__(256) void gather200(
    const u16* __restrict__ t, const float* __restrict__ dinv,
    const int* __restrict__ rows, const int* __restrict__ csr,
    u16* __restrict__ out, int N, int E)
{
  int wid = (blockIdx.x*blockDim.x + threadIdx.x) >> 6;
  int l = threadIdx.x & 63;
  if (wid >= N) return;
  int half = l >> 5, lh = l & 31;
  bool act = lh < 25;
  float dv = dinv[wid];
  int e0 = rows[wid];
  int e1 = (wid+1 < N) ? rows[wid+1] : E;
  const unsigned* base = (const unsigned*)t;
  float a0=0.f,a1=0.f,a2=0.f,a3=0.f,a4=0.f,a5=0.f,a6=0.f,a7=0.f;
  if (half == 0 && act){
    u32x4 sv = *((const u32x4*)(base + (size_t)wid*100) + lh);
    a0 = u2f_lo(sv[0]); a1 = u2f_hi(sv[0]);
    a2 = u2f_lo(sv[1]); a3 = u2f_hi(sv[1]);
    a4 = u2f_lo(sv[2]); a5 = u2f_hi(sv[2]);
    a6 = u2f_lo(sv[3]); a7 = u2f_hi(sv[3]);
  }
  for (int b0 = e0; b0 < e1; b0 += 64){
    int n = e1 - b0;
    int cnt = n < 64 ? n : 64;
    int myv = (l < cnt) ? csr[b0 + l] : 0;
    for (int i = 0; i < cnt; i += 16){
      int ss[8]; bool vld[8];
#pragma unroll
      for (int u=0;u<8;u++){
        int idx = i + 2*u + half;
        int ci = idx < cnt ? idx : cnt-1;
        ss[u] = __shfl(myv, ci);
        vld[u] = idx < cnt;
      }
      u32x4 P[8];
#pragma unroll
      for (int u=0;u<8;u++){
        u32x4 z = {0,0,0,0};
        P[u] = act ? *((const u32x4*)(base + (size_t)ss[u]*100) + lh) : z;
      }
#pragma unroll
      for (int u=0;u<8;u++){
        if (vld[u]){
          a0 += u2f_lo(P[u][0]); a1 += u2f_hi(P[u][0]);
          a2 += u2f_lo(P[u][1]); a3 += u2f_hi(P[u][1]);
          a4 += u2f_lo(P[u][2]); a5 += u2f_hi(P[u][2]);
          a6 += u2f_lo(P[u][3]); a7 += u2f_hi(P[u][3]);
        }
      }
    }
  }
  a0 += __shfl_xor(a0, 32); a1 += __shfl_xor(a1, 32);
  a2 += __shfl_xor(a2, 32); a3 += __shfl_xor(a3, 32);
  a4 += __shfl_xor(a4, 32); a5 += __shfl_xor(a5, 32);
  a6 += __shfl_xor(a6, 32); a7 += __shfl_xor(a7, 32);
  if (half == 0 && act){
    u32x4 wv;
    wv[0] = (unsigned)f2b(a0*dv) | ((unsigned)f2b(a1*dv) << 16);
    wv[1] = (unsigned)f2b(a2*dv) | ((unsigned)f2b(a3*dv) << 16);
    wv[2] = (unsigned)f2b(a4*dv) | ((unsigned)f2b(a5*dv) << 16);
    wv[3] = (unsigned)f2b(a6*dv) | ((unsigned)f2b(a7*dv) << 16);
    *((u32x4*)((unsigned*)out + (size_t)wid*100) + lh) = wv;
  }
}

// ===== single pack kernel: Pc1 (K=128, 4 steps) + Pc2 (K=200, 7 steps) =====
__device__ __forceinline__ void pack_one(const float* W, u16* Bp, int K, int idx){
  int l  = idx & 63;
  int nt = (idx >> 6) % NT;
  int kk = idx / (64*NT);
  int n  = nt*16 + (l & 15);
  int k0 = kk*32 + (l>>4)*8;
  u16 v[8];
#pragma unroll
  for (int e=0;e<8;e++){
    int k = k0 + e;
    v[e] = (k < K && n < HDIM) ? f2b(W[(size_t)k*HDIM + n]) : (u16)0;
  }
#pragma unroll
  for (int e=0;e<8;e++) Bp[(size_t)idx*8 + e] = v[e];
}
__global__ void pack_both(const float* __restrict__ Wc1, u16* __restrict__ Pc1,
                          const float* __restrict__ Wc2, u16* __restrict__ Pc2){
  int idx = blockIdx.x*blockDim.x + threadIdx.x;
  const int t1 = 4*NT*64;
  if (idx < t1) pack_one(Wc1, Pc1, 128, idx);
  else if (idx < t1 + 7*NT*64) pack_one(Wc2, Pc2, 200, idx - t1);
}

// ===== GEMM: 128 rows/block, 2 A-frags/wave; out = dinv[r]*relu(acc+bias) bf16[200] =====
template<int KSTEPS, int KACT>
__global__ __launch_bounds__(256) void gemm_h1(
    const u16* __restrict__ A, const u16* __restrict__ Bp,
    const float* __restrict__ bias, const float* __restrict__ dinv,
    u16* __restrict__ Out, int M, int Astride)
{
  const int w  = threadIdx.x >> 6;
  const int l  = threadIdx.x & 63;
  const int lm = l & 15;
  const int kg = l >> 4;
  const int base = blockIdx.x*128;
  int r0 = base + w*16 + lm;
  int r1 = r0 + 64;
  const u16* A0 = A + (size_t)(r0 < M ? r0 : 0) * Astride;
  const u16* A1 = A + (size_t)(r1 < M ? r1 : 0) * Astride;
  f32x4 acc[2][NT] = {};
  const s16x8 az = {0,0,0,0,0,0,0,0};
#pragma unroll
  for (int kk=0; kk<KSTEPS; ++kk){
    int k0 = kk*32 + kg*8;
    s16x8 a0 = (k0 < KACT) ? *(const s16x8*)(A0 + k0) : az;
    s16x8 a1 = (k0 < KACT) ? *(const s16x8*)(A1 + k0) : az;
    const u16* bp = Bp + ((size_t)kk*NT*64 + l)*8;
#pragma unroll
    for (int t=0;t<NT;t++){
      s16x8 b = *(const s16x8*)(bp + t*512);
      acc[0][t] = __builtin_amdgcn_mfma_f32_16x16x32_bf16(a0, b, acc[0][t], 0, 0, 0);
      acc[1][t] = __builtin_amdgcn_mfma_f32_16x16x32_bf16(a1, b, acc[1][t], 0, 0, 0);
    }
  }
#pragma unroll
  for (int m=0;m<2;m++){
    int orow = base + m*64 + w*16 + kg*4;   // C/D: col=lane&15, row=(lane>>4)*4+j
    float scj[4];
#pragma unroll
    for (int j=0;j<4;j++){ int r = orow + j; scj[j] = (r < M) ? dinv[r] : 0.f; }
#pragma unroll
    for (int t=0;t<NT;t++){
      int c = t*16 + lm;
      if (c < HDIM){
#pragma unroll
        for (int j=0;j<4;j++){
          int r = orow + j;
          if (r < M){
            float v = fmaxf(acc[m][t][j] + bias[c], 0.f) * scj[j];
            Out[(size_t)r*HDIM + c] = f2b(v);
          }
        }
      }
    }
  }
}

// ===== GEMM + fused mean-pool epilogue (per-wave LDS slices) =====
template<int KSTEPS, int KACT>
__global__ __launch_bounds__(256) void gemm_pool(
    const u16* __restrict__ A, const u16* __restrict__ Bp,
    const float* __restrict__ bias, float* __restrict__ pooled,
    int M, int Astride)
{
  __shared__ float ps[4][2][HDIM+8];
  for (int i = threadIdx.x; i < 4*2*(HDIM+8); i += 256) ((float*)ps)[i] = 0.f;
  __syncthreads();
  const int w  = threadIdx.x >> 6;
  const int l  = threadIdx.x & 63;
  const int lm = l & 15;
  const int kg = l >> 4;
  const int base = blockIdx.x*128;
  int r0 = base + w*16 + lm;
  int r1 = r0 + 64;
  const u16* A0 = A + (size_t)(r0 < M ? r0 : 0) * Astride;
  const u16* A1 = A + (size_t)(r1 < M ? r1 : 0) * Astride;
  f32x4 acc[2][NT] = {};
  const s16x8 az = {0,0,0,0,0,0,0,0};
#pragma unroll
  for (int kk=0; kk<KSTEPS; ++kk){
    int k0 = kk*32 + kg*8;
    s16x8 a0 = (k0 < KACT) ? *(const s16x8*)(A0 + k0) : az;
    s16x8 a1 = (k0 < KACT) ? *(const s16x8*)(A1 + k0) : az;
    const u16* bp = Bp + ((size_t)kk*NT*64 + l)*8;
#pragma unroll
    for (int t=0;t<NT;t++){
      s16x8 b = *(const s16x8*)(bp + t*512);
      acc[0][t] = __builtin_amdgcn_mfma_f32_16x16x32_bf16(a0, b, acc[0][t], 0, 0, 0);
      acc[1][t] = __builtin_amdgcn_mfma_f32_16x16x32_bf16(a1, b, acc[1][t], 0, 0, 0);
    }
  }
  const int g0 = base / NPG;
#pragma unroll
  for (int m=0;m<2;m++){
    int R0 = base + m*64 + w*16;
    bool uni = (R0 + 15 < M) && ((R0/NPG) == ((R0+15)/NPG));
    int slotU = (R0/NPG) - g0;
#pragma unroll
    for (int t=0;t<NT;t++){
      int c = t*16 + lm;
      if (c < HDIM){
        float v0 = fmaxf(acc[m][t][0] + bias[c], 0.f);
        float v1 = fmaxf(acc[m][t][1] + bias[c], 0.f);
        float v2 = fmaxf(acc[m][t][2] + bias[c], 0.f);
        float v3 = fmaxf(acc[m][t][3] + bias[c], 0.f);
        if (uni){
          float s = v0+v1+v2+v3;
          s += __shfl_xor(s, 16);
          s += __shfl_xor(s, 32);
          if (kg == 0) ps[w][slotU][c] += s;
        } else {
          float s0 = 0.f, s1 = 0.f;
          float vv[4] = {v0,v1,v2,v3};
#pragma unroll
          for (int j=0;j<4;j++){
            int r = R0 + kg*4 + j;
            if (r < M){
              if ((r/NPG) - g0 == 0) s0 += vv[j]; else s1 += vv[j];
            }
          }
          s0 += __shfl_xor(s0, 16); s0 += __shfl_xor(s0, 32);
          s1 += __shfl_xor(s1, 16); s1 += __shfl_xor(s1, 32);
          if (kg == 0){ ps[w][0][c] += s0; ps[w][1][c] += s1; }
        }
      }
    }
  }
  __syncthreads();
  for (int i = threadIdx.x; i < 2*HDIM; i += 256){
    int slot = i / HDIM, c = i % HDIM;
    float s = ps[0][slot][c] + ps[1][slot][c] + ps[2][slot][c] + ps[3][slot][c];
    int g = g0 + slot;
    if (g < B_CLLN && s != 0.f) unsafeAtomicAdd(&pooled[g*HDIM + c], s);
  }
}

// ================= xc = pooled/NPG @ Wlc + blc =================
__global__ void xc_kernel(const float* __restrict__ pooled, const float* __restrict__ Wlc,
                          const float* __restrict__ blc, float* __restrict__ xc){
  __shared__ float p[HDIM];
  int b = blockIdx.x, j = threadIdx.x;
  if (j < HDIM) p[j] = pooled[b*HDIM + j] * (1.0f/NPG);
  __syncthreads();
  float s = blc[j];
  for (int k=0;k<HDIM;k++) s += p[k]*Wlc[(size_t)k*256 + j];
  xc[(size_t)b*256 + j] = s;
}

// ===== bio frontier: Y1 rows (f32) for {last} ∪ nbrs(last) only =====
__global__ void bio_front(const float* __restrict__ x_bio, const float* __restrict__ dinvAll,
                          const int* __restrict__ rowAll, const int* __restrict__ csr,
                          float* __restrict__ Y1f, float* __restrict__ dvF){
  const float* dinvB = dinvAll + N_CLLN;
  int g0l = rowAll[NTOT - 1];
  int fcnt = (ETOT - g0l) + 1; if (fcnt > FCAP) fcnt = FCAP;
  int wid = (blockIdx.x*blockDim.x + threadIdx.x) >> 6;
  int nw  = (gridDim.x*blockDim.x) >> 6;
  int l = threadIdx.x & 63;
  for (int k = wid; k < fcnt; k += nw){
    int v = (k == 0) ? (N_BION - 1) : csr[g0l + k - 1];
    float dv = dinvB[v];
    int e0 = rowAll[N_CLLN + v];
    int e1 = (v + 1 < N_BION) ? rowAll[N_CLLN + v + 1] : ETOT;
    float c0 = x_bio[(size_t)v*128 + l]      * dv;
    float c1 = x_bio[(size_t)v*128 + l + 64] * dv;
    for (int e = e0; e < e1; ++e){
      int s = csr[e];
      float ds = dinvB[s];
      c0 += x_bio[(size_t)s*128 + l]      * ds;
      c1 += x_bio[(size_t)s*128 + l + 64] * ds;
    }
    Y1f[(size_t)k*128 + l]      = c0 * dv;
    Y1f[(size_t)k*128 + l + 64] = c1 * dv;
    if (l == 0) dvF[k] = dv;
  }
}

// ===== bio h1-accumulate: parallel over frontier rows =====
__global__ __launch_bounds__(256) void bio_h1acc(
    const float* __restrict__ Y1f, const float* __restrict__ dvF,
    const int* __restrict__ rowAll,
    const float* __restrict__ Wb1, const float* __restrict__ bb1,
    float* __restrict__ Y2acc){
  __shared__ float y1[128];
  int tid = threadIdx.x;
  int g0l = rowAll[NTOT - 1];
  int fcnt = (ETOT - g0l) + 1; if (fcnt > FCAP) fcnt = FCAP;
  for (int k = blockIdx.x; k < fcnt; k += gridDim.x){
    if (tid < 128) y1[tid] = Y1f[(size_t)k*128 + tid];
    __syncthreads();
    if (tid < HDIM){
      float s = bb1[tid];
#pragma unroll 8
      for (int q=0;q<128;q++) s += y1[q]*Wb1[q*HDIM + tid];
      unsafeAtomicAdd(&Y2acc[tid], fmaxf(s, 0.f)*dvF[k]);
    }
    __syncthreads();
  }
}

// ===== bio finish =====
__global__ void bio_fin(const float* __restrict__ Y2acc, const float* __restrict__ dinvAll,
                        const float* __restrict__ Wb2, const float* __restrict__ bb2,
                        const float* __restrict__ Wlb, const float* __restrict__ blb,
                        float* __restrict__ xb){
  __shared__ float Y2[HDIM];
  __shared__ float wv[HDIM];
  int tid = threadIdx.x;
  float dl = dinvAll[NTOT - 1];
  if (tid < HDIM) Y2[tid] = Y2acc[tid] * dl;
  __syncthreads();
  if (tid < HDIM){
    float s = bb2[tid];
#pragma unroll 8
    for (int q=0;q<HDIM;q++) s += Y2[q]*Wb2[q*HDIM + tid];
    wv[tid] = fmaxf(s, 0.f);
  }
  __syncthreads();
  if (tid < 128){
    float s = blb[tid];
#pragma unroll 8
    for (int c=0;c<HDIM;c++) s += wv[c]*Wlb[c*128 + tid];
    xb[tid] = s;
  }
}

// ================= mol branch (multi-block, all fp32) =================
__global__ void mol_agg(const float* __restrict__ x, const int* __restrict__ src,
                        const int* __restrict__ dst, float* __restrict__ a, int E, int F){
  int idx = blockIdx.x*blockDim.x + threadIdx.x;
  if (idx >= E*F) return;
  int e = idx / F, f = idx % F;
  unsafeAtomicAdd(&a[dst[e]*F + f], x[(size_t)src[e]*F + f]);
}
__global__ void mol_l1(const float* __restrict__ x, const float* __restrict__ a1,
                       const float* __restrict__ Wrel, const float* __restrict__ brel,
                       const float* __restrict__ Wroot, float* __restrict__ m1){
  int idx = blockIdx.x*blockDim.x + threadIdx.x;
  if (idx >= N_MOLN*HDIM) return;
  int i = idx / HDIM, c = idx % HDIM;
  float s = brel[c];
  for (int k=0;k<64;k++){
    s += a1[i*64+k]*Wrel[k*HDIM+c];
    s += x[i*64+k]*Wroot[k*HDIM+c];
  }
  m1[idx] = fmaxf(s, 0.f);
}
__global__ void mol_l2(const float* __restrict__ m1, const float* __restrict__ a2,
                       const float* __restrict__ Wrel2, const float* __restrict__ brel2,
                       const float* __restrict__ Wroot2, float* __restrict__ colsum){
  int idx = blockIdx.x*blockDim.x + threadIdx.x;
  if (idx >= N_MOLN*HDIM) return;
  int i = idx / HDIM, c = idx % HDIM;
  float s = brel2[c];
  for (int k=0;k<HDIM;k++){
    s += a2[i*HDIM+k]*Wrel2[k*HDIM+c] + m1[i*HDIM+k]*Wroot2[k*HDIM+c];
  }
  s = fmaxf(s, 0.f);
  unsafeAtomicAdd(&colsum[c], s*(1.0f/N_MOLN));
}
__global__ void mol_head(const float* __restrict__ colsum, const float* __restrict__ Wlm,
                         const float* __restrict__ blm, float* __restrict__ xm){
  int j = threadIdx.x;
  if (j >= 128) return;
  float s = blm[j];
  for (int c=0;c<HDIM;c++) s += colsum[c]*Wlm[c*128+j];
  xm[j] = s;
}

// ================= bilinear score =================
__global__ void score_kernel(const float* __restrict__ xc, const float* __restrict__ W,
                             const float* __restrict__ bias, const float* __restrict__ xm,
                             const float* __restrict__ xb, float* __restrict__ out){
  __shared__ float xd[256];
  __shared__ float u[256];
  int tid = threadIdx.x;
  xd[tid] = (tid < 128) ? xm[tid] : xb[tid-128];
  __syncthreads();
  float s = 0.f;
  for (int j=0;j<256;j++) s += W[(size_t)tid*256 + j]*xd[j];
  u[tid] = s;
  __syncthreads();
  if (tid < B_CLLN){
    float sc = bias[0];
    const float* xr = xc + (size_t)tid*256;
    for (int i=0;i<256;i++) sc += xr[i]*u[i];
    out[tid] = sc;
  }
}

extern "C" void kernel_launch(void* const* d_in, const int* in_sizes, int n_in,
                              void* d_out, int out_size, void* d_ws, size_t ws_size,
                              hipStream_t stream) {
  const float* x_cll = (const float*)d_in[0];
  const float* x_mol = (const float*)d_in[1];
  const float* x_bio = (const float*)d_in[2];
  const int* e_cll = (const int*)d_in[3];
  const int* e_mol = (const int*)d_in[5];
  const int* e_bio = (const int*)d_in[6];
  const float *Wc1=(const float*)d_in[7],  *bc1=(const float*)d_in[8];
  const float *Wc2=(const float*)d_in[9],  *bc2=(const float*)d_in[10];
  const float *Wlc=(const float*)d_in[11], *blc=(const float*)d_in[12];
  const float *Wrel1=(const float*)d_in[13],*brel1=(const float*)d_in[14],*Wroot1=(const float*)d_in[15];
  const float *Wrel2=(const float*)d_in[16],*brel2=(const float*)d_in[17],*Wroot2=(const float*)d_in[18];
  const float *Wlm=(const float*)d_in[19], *blm=(const float*)d_in[20];
  const float *Wb1=(const float*)d_in[21], *bb1=(const float*)d_in[22];
  const float *Wb2=(const float*)d_in[23], *bb2=(const float*)d_in[24];
  const float *Wlb=(const float*)d_in[25], *blb=(const float*)d_in[26];
  const float *Wbl=(const float*)d_in[27], *bias=(const float*)d_in[28];
  float* out = (float*)d_out;

  char* ws = (char*)d_ws;
  size_t o = 0;
  auto alloc = [&](size_t bytes)->char*{
    char* p = ws + o;
    o = (o + bytes + 255) & ~(size_t)255;
    return p;
  };
  u16*   XS    = (u16*)  alloc((size_t)N_CLLN*128*2);
  u16*   Y1    = (u16*)  alloc((size_t)N_CLLN*128*2);
  u16*   BUF1  = (u16*)  alloc((size_t)N_CLLN*HDIM*2 + 512);  // +slack for 16B tails
  u16*   BUF2  = (u16*)  alloc((size_t)N_CLLN*HDIM*2 + 512);
  float* dinvA = (float*)alloc((size_t)NTOT*4);
  int*   cntA  = (int*)  alloc((size_t)NTOT*4);     // zeroed
  int*   rowA  = (int*)  alloc((size_t)NTOT*4);
  int*   csrA  = (int*)  alloc((size_t)ETOT*4);
  int*   eidx  = (int*)  alloc((size_t)ETOT*4);
  int*   bsum  = (int*)  alloc(256*4);
  float* pooled= (float*)alloc((size_t)B_CLLN*HDIM*4);   // zeroed
  float* xc    = (float*)alloc((size_t)B_CLLN*256*4);
  float* a1    = (float*)alloc((size_t)(N_MOLN*64 + N_MOLN*HDIM + 2*HDIM)*4);  // zero region
  float* a2    = a1 + N_MOLN*64;
  float* colsum= a2 + N_MOLN*HDIM;
  float* Y2acc = colsum + HDIM;
  float* m1    = (float*)alloc((size_t)N_MOLN*HDIM*4);
  float* xm    = (float*)alloc(128*4);
  float* xb    = (float*)alloc(128*4);
  float* Y1f   = (float*)alloc((size_t)FCAP*128*4);
  float* dvF   = (float*)alloc((size_t)FCAP*4);
  u16* Pc1 = (u16*)alloc((size_t)4*NT*64*8*2);
  u16* Pc2 = (u16*)alloc((size_t)7*NT*64*8*2);
  if (o > ws_size) return;
  (void)in_sizes; (void)n_in; (void)out_size;

  hipMemsetAsync(cntA, 0, (size_t)NTOT*4, stream);
  hipMemsetAsync(pooled, 0, (size_t)B_CLLN*HDIM*4, stream);
  hipMemsetAsync(a1, 0, (size_t)(N_MOLN*64 + N_MOLN*HDIM + 2*HDIM)*4, stream);

  pack_both<<<(11*NT*64+255)/256, 256, 0, stream>>>(Wc1, Pc1, Wc2, Pc2);

  // ---- combined CSR build (atomic-free scatter via eidx; dinv fused into scan1) ----
  hist_all<<<(ETOT+255)/256, 256, 0, stream>>>(e_cll, e_bio, cntA, eidx);
  scan1<<<(NTOT+1023)/1024, 256, 0, stream>>>(cntA, dinvA, rowA, bsum, NTOT);
  scan2<<<1, 256, 0, stream>>>(bsum, (NTOT+1023)/1024);
  scan3<<<(NTOT+255)/256, 256, 0, stream>>>(rowA, bsum, NTOT);
  scatter_all<<<(ETOT+255)/256, 256, 0, stream>>>(e_cll, e_bio, rowA, eidx, csrA);

  const int wcll = (N_CLLN+3)/4;
  const int mcll = (N_CLLN+127)/128;

  // ---- cll branch ----
  prescale128<<<(N_CLLN*16+255)/256, 256, 0, stream>>>(x_cll, dinvA, XS, N_CLLN);
  gather128<<<wcll, 256, 0, stream>>>(XS, dinvA, rowA, csrA, Y1, N_CLLN, E_CLLN);
  gemm_h1<4,128><<<mcll, 256, 0, stream>>>(Y1, Pc1, bc1, dinvA, BUF1, N_CLLN, 128);
  gather200<<<wcll, 256, 0, stream>>>(BUF1, dinvA, rowA, csrA, BUF2, N_CLLN, E_CLLN);
  gemm_pool<7,200><<<mcll, 256, 0, stream>>>(BUF2, Pc2, bc2, pooled, N_CLLN, HDIM);
  xc_kernel<<<B_CLLN, 256, 0, stream>>>(pooled, Wlc, blc, xc);

  // ---- bio branch: frontier only, parallel tail ----
  bio_front<<<16, 256, 0, stream>>>(x_bio, dinvA, rowA, csrA, Y1f, dvF);
  bio_h1acc<<<64, 256, 0, stream>>>(Y1f, dvF, rowA, Wb1, bb1, Y2acc);
  bio_fin<<<1, 256, 0, stream>>>(Y2acc, dinvA, Wb2, bb2, Wlb, blb, xb);

  // ---- mol branch (multi-block) ----
  mol_agg<<<(E_MOLN*64+255)/256, 256, 0, stream>>>(x_mol, e_mol, e_mol + E_MOLN, a1, E_MOLN, 64);
  mol_l1<<<(N_MOLN*HDIM+255)/256, 256, 0, stream>>>(x_mol, a1, Wrel1, brel1, Wroot1, m1);
  mol_agg<<<(E_MOLN*HDIM+255)/256, 256, 0, stream>>>(m1, e_mol, e_mol + E_MOLN, a2, E_MOLN, HDIM);
  mol_l2<<<(N_MOLN*HDIM+255)/256, 256, 0, stream>>>(m1, a2, Wrel2, brel2, Wroot2, colsum);
  mol_head<<<1, 128, 0, stream>>>(colsum, Wlm, blm, xm);

  // ---- score ----
  score_kernel<<<1, 256, 0, stream>>>(xc, Wbl, bias, xm, xb, out);
}